// Round 5
// baseline (346.027 us; speedup 1.0000x reference)
//
#include <hip/hip_runtime.h>
#include <math.h>

#define H_SIZE   4096
#define N_HEADS  32
#define N_KV     8
#define HEAD_DIM 128
#define GROUP    4
#define Q_SIZE   4096
#define KV_SIZE  1024
#define QKV_OUT  6144          // Q_SIZE + 2*KV_SIZE
#define NUM_SEQS 64
#define MAX_CTX  2048
#define BLK_SZ   16
#define BLOCKS_PER_SEQ 128
#define ATT_SCALE 0.08838834764831845f   // 128^-0.5

#define CHUNK    256
#define NCHUNK   8             // MAX_CTX / CHUNK
#define SUBT     64            // K tokens staged in LDS per subtile
#define KPAD     129           // LDS row pad: bank = (lane + j) % 32 -> <=2-way
#define KSPLIT   8
#define KCHUNK   512           // H_SIZE / KSPLIT

typedef __attribute__((ext_vector_type(8))) short bf16x8;
typedef __attribute__((ext_vector_type(4))) float f32x4;

__device__ __forceinline__ short f2bf(float f) {
    return __builtin_bit_cast(short, (__bf16)f);   // lowers to v_cvt_pk_bf16_f32
}

__device__ __forceinline__ bf16x8 cvt8(float4 a, float4 b) {
    bf16x8 r;
    r[0]=f2bf(a.x); r[1]=f2bf(a.y); r[2]=f2bf(a.z); r[3]=f2bf(a.w);
    r[4]=f2bf(b.x); r[5]=f2bf(b.y); r[6]=f2bf(b.z); r[7]=f2bf(b.w);
    return r;
}

// ---------------- fp32 -> bf16 bulk convert (X operand, done once) ----------------
__global__ __launch_bounds__(256)
void cvt_bf16(const float* __restrict__ in, unsigned short* __restrict__ out, int n4) {
    int i = blockIdx.x * 256 + threadIdx.x;
    if (i >= n4) return;
    float4 v = *(const float4*)(in + (size_t)i * 4);
    ushort2 lo = { (unsigned short)f2bf(v.x), (unsigned short)f2bf(v.y) };
    ushort2 hi = { (unsigned short)f2bf(v.z), (unsigned short)f2bf(v.w) };
    *(ushort2*)(out + (size_t)i * 4)     = lo;
    *(ushort2*)(out + (size_t)i * 4 + 2) = hi;
}

// ---------------- MFMA GEMM: Yp[c][64][N] = A[64][4096] @ W[N][4096]^T ----------
__global__ __launch_bounds__(256)
void gemm_mfma(const unsigned short* __restrict__ A, const float* __restrict__ W,
               float* __restrict__ Yp, int N) {
    const int n0   = blockIdx.x * 64;
    const int k0   = blockIdx.y * KCHUNK;
    const int wave = threadIdx.x >> 6;
    const int lane = threadIdx.x & 63;
    const int ncol = n0 + wave * 16 + (lane & 15);
    const int klane = (lane >> 4) * 8;

    const float*          wrow = W + (size_t)ncol * H_SIZE + k0 + klane;
    const unsigned short* arow = A + (size_t)(lane & 15) * H_SIZE + k0 + klane;

    f32x4 acc[4] = {};
    #pragma unroll 2
    for (int k = 0; k < KCHUNK; k += 32) {
        float4 wa = *(const float4*)(wrow + k);
        float4 wb = *(const float4*)(wrow + k + 4);
        bf16x8 bf = cvt8(wa, wb);
        #pragma unroll
        for (int m = 0; m < 4; ++m) {
            bf16x8 af = *(const bf16x8*)(const void*)(arow + (size_t)m * 16 * H_SIZE + k);
            acc[m] = __builtin_amdgcn_mfma_f32_16x16x32_bf16(af, bf, acc[m], 0, 0, 0);
        }
    }
    float* yp = Yp + (size_t)blockIdx.y * 64 * N;
    #pragma unroll
    for (int m = 0; m < 4; ++m)
        #pragma unroll
        for (int j = 0; j < 4; ++j)
            yp[(size_t)(m * 16 + (lane >> 4) * 4 + j) * N + ncol] = acc[m][j];
}

// ---------------- fused K-split reduce + RoPE for QKV ----------------
__global__ __launch_bounds__(256)
void qkv_reduce_rope(const float* __restrict__ Yp, float* __restrict__ qkv,
                     const int* __restrict__ positions) {
    const int s   = blockIdx.x;
    const int idx = blockIdx.y * 256 + threadIdx.x;
    const float pos = (float)positions[s];
    if (idx < 2560) {
        const int head = idx >> 6, d = idx & 63;
        const int j1 = (head < N_HEADS ? head * HEAD_DIM
                                       : Q_SIZE + (head - N_HEADS) * HEAD_DIM) + d;
        const int j2 = j1 + 64;
        float x1 = 0.f, x2 = 0.f;
        #pragma unroll
        for (int c = 0; c < KSPLIT; ++c) {
            x1 += Yp[((size_t)c * 64 + s) * QKV_OUT + j1];
            x2 += Yp[((size_t)c * 64 + s) * QKV_OUT + j2];
        }
        const float inv_freq = powf(10000.0f, -(float)d / 64.0f);
        const float ang = pos * inv_freq;
        const float cs = cosf(ang), sn = sinf(ang);
        qkv[(size_t)s * QKV_OUT + j1] = x1 * cs - x2 * sn;
        qkv[(size_t)s * QKV_OUT + j2] = x2 * cs + x1 * sn;
    } else if (idx < 3584) {
        const int j = Q_SIZE + KV_SIZE + (idx - 2560);
        float v = 0.f;
        #pragma unroll
        for (int c = 0; c < KSPLIT; ++c)
            v += Yp[((size_t)c * 64 + s) * QKV_OUT + j];
        qkv[(size_t)s * QKV_OUT + j] = v;
    }
}

__global__ __launch_bounds__(256)
void reduce_ksplit(const float* __restrict__ Yp, float* __restrict__ Y, int total) {
    int i = blockIdx.x * 256 + threadIdx.x;
    if (i >= total) return;
    float s = 0.f;
    #pragma unroll
    for (int c = 0; c < KSPLIT; ++c) s += Yp[(size_t)c * total + i];
    Y[i] = s;
}

// ---------------- Flash-decode attention: per-chunk partials ----------------
// K staged in LDS via fully-coalesced float4 loads; scores computed from LDS
// (lane = token, wave = q-head; pad-129 rows -> <=2-way bank conflicts).
__global__ __launch_bounds__(256)
void attn_chunk(const float* __restrict__ qkv,
                const float* __restrict__ k_cache,
                const float* __restrict__ v_cache,
                const int*   __restrict__ block_tables,
                const int*   __restrict__ context_lens,
                float* __restrict__ pacc,   // [sh][c][g][128]
                float* __restrict__ pml) {  // [sh][c][g][2]
    const int sh = blockIdx.x;
    const int s  = sh >> 3;
    const int h  = sh & 7;
    const int c  = blockIdx.y;
    const int ctx = context_lens[s];
    if (c * CHUNK >= ctx) return;
    const int pos = ctx - 1;
    const int nvalid = min(CHUNK, ctx - c * CHUNK);

    // smem layout: [0, 8256) Ks[64][129]  (reused as red[4][4][128] in PV phase)
    //              [8256, 8768) qs[4][128]
    //              [8768, 9792) sc[4][256]
    //              [9792, 9800) mls[4][2]
    __shared__ float smem[9800];
    float (*Ks)[KPAD]              = (float (*)[KPAD])smem;
    float (*red)[GROUP][HEAD_DIM]  = (float (*)[GROUP][HEAD_DIM])smem;
    float (*qs)[HEAD_DIM]          = (float (*)[HEAD_DIM])(smem + 8256);
    float (*sc)[CHUNK]             = (float (*)[CHUNK])(smem + 8768);
    float *mls                     = smem + 9792;

    const int tid  = threadIdx.x;
    const int wave = tid >> 6;
    const int lane = tid & 63;

    for (int idx = tid; idx < GROUP * HEAD_DIM; idx += 256) {
        int g = idx >> 7, d = idx & 127;
        qs[g][d] = qkv[(size_t)s * QKV_OUT + (h * GROUP + g) * HEAD_DIM + d];
    }

    const int*   bt   = block_tables + s * BLOCKS_PER_SEQ;
    const float* knew = qkv + (size_t)s * QKV_OUT + Q_SIZE + h * HEAD_DIM;
    const float* vnew = qkv + (size_t)s * QKV_OUT + Q_SIZE + KV_SIZE + h * HEAD_DIM;

    // ---- phase 1: stage K subtile -> LDS, then scores ----
    for (int st = 0; st < CHUNK / SUBT; ++st) {
        const int i0 = st * SUBT;
        __syncthreads();                 // prev compute done (covers qs for st=0)
        if (i0 < nvalid) {
            #pragma unroll
            for (int r = 0; r < 8; ++r) {
                int slot = tid + r * 256;       // 0..2047
                int row  = slot >> 5;           // 0..63
                int c4   = slot & 31;           // float4 index in row
                int i    = i0 + row;
                float4 kv = make_float4(0.f, 0.f, 0.f, 0.f);
                if (i < nvalid) {
                    int t = c * CHUNK + i;
                    const float* kp;
                    if (t == pos) kp = knew;
                    else {
                        int blk = bt[t >> 4];
                        kp = k_cache + ((size_t)(blk * BLK_SZ + (t & 15)) * N_KV + h) * HEAD_DIM;
                    }
                    kv = *(const float4*)(kp + c4 * 4);
                }
                float* dst = &Ks[row][c4 * 4];
                dst[0] = kv.x; dst[1] = kv.y; dst[2] = kv.z; dst[3] = kv.w;
            }
            __syncthreads();
            // wave g computes 64 scores (lane = token) for head g
            const int g = wave;
            float dot = 0.f;
            #pragma unroll
            for (int dt = 0; dt < 4; ++dt) {
                #pragma unroll
                for (int j = 0; j < 8; ++j) {
                    float4 q4 = *(const float4*)(&qs[g][dt * 32 + j * 4]);
                    const float* kr = &Ks[lane][dt * 32 + j * 4];
                    dot = fmaf(kr[0], q4.x, fmaf(kr[1], q4.y,
                          fmaf(kr[2], q4.z, fmaf(kr[3], q4.w, dot))));
                }
            }
            const int i = i0 + lane;
            sc[g][i] = (i < nvalid) ? dot * ATT_SCALE : -1e30f;
        } else {
            sc[wave][i0 + lane] = -1e30f;
        }
    }
    __syncthreads();

    // ---- chunk-local softmax: wave g owns head g ----
    {
        const int g = wave;
        float m = -1e30f;
        #pragma unroll
        for (int r = 0; r < 4; ++r) m = fmaxf(m, sc[g][lane + r * 64]);
        #pragma unroll
        for (int off = 32; off; off >>= 1) m = fmaxf(m, __shfl_xor(m, off));
        float l = 0.f;
        #pragma unroll
        for (int r = 0; r < 4; ++r) {
            float e = __expf(sc[g][lane + r * 64] - m);
            sc[g][lane + r * 64] = e;
            l += e;
        }
        #pragma unroll
        for (int off = 32; off; off >>= 1) l += __shfl_xor(l, off);
        if (lane == 0) { mls[g * 2] = m; mls[g * 2 + 1] = l; }
    }
    __syncthreads();

    // ---- phase 2: PV, coalesced float2 V rows (red aliases Ks; safe after sync) ----
    float2 acc[GROUP] = {};
    int cnt = nvalid - wave * 64;
    if (cnt > 64) cnt = 64;
    #pragma unroll 2
    for (int ii = 0; ii < cnt; ++ii) {
        const int i = wave * 64 + ii;
        const int t = c * CHUNK + i;
        const float* vp;
        if (t == pos) vp = vnew;
        else {
            int blk = bt[t >> 4];
            vp = v_cache + ((size_t)(blk * BLK_SZ + (t & 15)) * N_KV + h) * HEAD_DIM;
        }
        float2 vv = *(const float2*)(vp + lane * 2);
        #pragma unroll
        for (int g = 0; g < GROUP; ++g) {
            float p = sc[g][i];
            acc[g].x = fmaf(p, vv.x, acc[g].x);
            acc[g].y = fmaf(p, vv.y, acc[g].y);
        }
    }
    #pragma unroll
    for (int g = 0; g < GROUP; ++g) {
        red[wave][g][lane*2]   = acc[g].x;
        red[wave][g][lane*2+1] = acc[g].y;
    }
    __syncthreads();

    {
        const int g = wave;
        float ox = red[0][g][lane*2]   + red[1][g][lane*2]   + red[2][g][lane*2]   + red[3][g][lane*2];
        float oy = red[0][g][lane*2+1] + red[1][g][lane*2+1] + red[2][g][lane*2+1] + red[3][g][lane*2+1];
        size_t idx = ((size_t)sh * NCHUNK + c) * GROUP + g;
        pacc[idx * HEAD_DIM + lane*2]     = ox;
        pacc[idx * HEAD_DIM + lane*2 + 1] = oy;
        if (lane == 0) { pml[idx*2] = mls[g*2]; pml[idx*2+1] = mls[g*2+1]; }
    }
}

// ---------------- combine chunk partials; emit bf16 for the O-GEMM ----------------
__global__ __launch_bounds__(256)
void attn_reduce(const float* __restrict__ pacc, const float* __restrict__ pml,
                 const int* __restrict__ context_lens, unsigned short* __restrict__ outbf) {
    const int sh = blockIdx.x;
    const int s  = sh >> 3;
    const int h  = sh & 7;
    const int g    = threadIdx.x >> 6;
    const int lane = threadIdx.x & 63;
    const int ctx = context_lens[s];
    const int nc  = (ctx + CHUNK - 1) / CHUNK;

    float M = -1e30f;
    for (int cc = 0; cc < nc; ++cc)
        M = fmaxf(M, pml[(((size_t)sh * NCHUNK + cc) * GROUP + g) * 2]);
    float ox = 0.f, oy = 0.f, L = 0.f;
    for (int cc = 0; cc < nc; ++cc) {
        size_t idx = ((size_t)sh * NCHUNK + cc) * GROUP + g;
        float w = __expf(pml[idx*2] - M);
        L = fmaf(w, pml[idx*2+1], L);
        float2 pa = *(const float2*)(pacc + idx * HEAD_DIM + lane*2);
        ox = fmaf(w, pa.x, ox);
        oy = fmaf(w, pa.y, oy);
    }
    float inv = 1.0f / L;
    unsigned short* op = outbf + (size_t)s * Q_SIZE + (h * GROUP + g) * HEAD_DIM;
    ushort2 o2 = { (unsigned short)f2bf(ox * inv), (unsigned short)f2bf(oy * inv) };
    *(ushort2*)(op + lane * 2) = o2;
}

extern "C" void kernel_launch(void* const* d_in, const int* in_sizes, int n_in,
                              void* d_out, int out_size, void* d_ws, size_t ws_size,
                              hipStream_t stream) {
    const int*   positions    = (const int*)  d_in[0];
    const float* hidden       = (const float*)d_in[1];
    const float* k_cache      = (const float*)d_in[2];
    const float* v_cache      = (const float*)d_in[3];
    const int*   block_tables = (const int*)  d_in[4];
    const int*   context_lens = (const int*)  d_in[5];
    const float* W_qkv        = (const float*)d_in[6];
    const float* W_o          = (const float*)d_in[7];
    float* out = (float*)d_out;

    float* qkv_ws = (float*)d_ws;                                     // 393216 f
    unsigned short* hidden_bf = (unsigned short*)(qkv_ws + (size_t)NUM_SEQS * QKV_OUT);
    unsigned short* attn_bf   = hidden_bf + (size_t)NUM_SEQS * H_SIZE;
    float* scratch = (float*)(attn_bf + (size_t)NUM_SEQS * H_SIZE);
    float* pacc = scratch;
    float* pml  = scratch + (size_t)NUM_SEQS * N_KV * NCHUNK * GROUP * HEAD_DIM;

    // 0) X -> bf16 (once)
    cvt_bf16<<<(NUM_SEQS * H_SIZE / 4 + 255) / 256, 256, 0, stream>>>(
        hidden, hidden_bf, NUM_SEQS * H_SIZE / 4);
    // 1) QKV projection + fused reduce+RoPE
    gemm_mfma<<<dim3(QKV_OUT / 64, KSPLIT), 256, 0, stream>>>(hidden_bf, W_qkv, scratch, QKV_OUT);
    qkv_reduce_rope<<<dim3(NUM_SEQS, 14), 256, 0, stream>>>(scratch, qkv_ws, positions);
    // 2) flash-decode attention
    attn_chunk<<<dim3(NUM_SEQS * N_KV, NCHUNK), 256, 0, stream>>>(
        qkv_ws, k_cache, v_cache, block_tables, context_lens, pacc, pml);
    attn_reduce<<<NUM_SEQS * N_KV, 256, 0, stream>>>(pacc, pml, context_lens, attn_bf);
    // 3) output projection + reduce
    gemm_mfma<<<dim3(Q_SIZE / 64, KSPLIT), 256, 0, stream>>>(attn_bf, W_o, scratch, Q_SIZE);
    reduce_ksplit<<<(NUM_SEQS * Q_SIZE + 255) / 256, 256, 0, stream>>>(scratch, out, NUM_SEQS * Q_SIZE);
}

// Round 6
// 260.157 us; speedup vs baseline: 1.3301x; 1.3301x over previous
//
#include <hip/hip_runtime.h>
#include <math.h>

#define H_SIZE   4096
#define N_HEADS  32
#define N_KV     8
#define HEAD_DIM 128
#define GROUP    4
#define Q_SIZE   4096
#define KV_SIZE  1024
#define QKV_OUT  6144          // Q_SIZE + 2*KV_SIZE
#define NUM_SEQS 64
#define MAX_CTX  2048
#define BLK_SZ   16
#define BLOCKS_PER_SEQ 128
#define ATT_SCALE 0.08838834764831845f   // 128^-0.5

#define CHUNK    64            // tokens per attn workgroup (= 4 cache blocks)
#define NCHUNK   32            // MAX_CTX / CHUNK
#define KSPLIT   8
#define KCHUNK   512           // H_SIZE / KSPLIT

typedef __attribute__((ext_vector_type(8))) short bf16x8;
typedef __attribute__((ext_vector_type(4))) float f32x4;

__device__ __forceinline__ short f2bf(float f) {
    return __builtin_bit_cast(short, (__bf16)f);   // lowers to v_cvt_pk_bf16_f32
}

__device__ __forceinline__ bf16x8 cvt8(float4 a, float4 b) {
    bf16x8 r;
    r[0]=f2bf(a.x); r[1]=f2bf(a.y); r[2]=f2bf(a.z); r[3]=f2bf(a.w);
    r[4]=f2bf(b.x); r[5]=f2bf(b.y); r[6]=f2bf(b.z); r[7]=f2bf(b.w);
    return r;
}

// ---------------- fp32 -> bf16 bulk convert (X operand, done once) ----------------
__global__ __launch_bounds__(256)
void cvt_bf16(const float* __restrict__ in, unsigned short* __restrict__ out, int n4) {
    int i = blockIdx.x * 256 + threadIdx.x;
    if (i >= n4) return;
    float4 v = *(const float4*)(in + (size_t)i * 4);
    ushort2 lo = { (unsigned short)f2bf(v.x), (unsigned short)f2bf(v.y) };
    ushort2 hi = { (unsigned short)f2bf(v.z), (unsigned short)f2bf(v.w) };
    *(ushort2*)(out + (size_t)i * 4)     = lo;
    *(ushort2*)(out + (size_t)i * 4 + 2) = hi;
}

// ---------------- MFMA GEMM: Yp[c][64][N] = A[64][4096] @ W[N][4096]^T ----------
__global__ __launch_bounds__(256)
void gemm_mfma(const unsigned short* __restrict__ A, const float* __restrict__ W,
               float* __restrict__ Yp, int N) {
    const int n0   = blockIdx.x * 64;
    const int k0   = blockIdx.y * KCHUNK;
    const int wave = threadIdx.x >> 6;
    const int lane = threadIdx.x & 63;
    const int ncol = n0 + wave * 16 + (lane & 15);
    const int klane = (lane >> 4) * 8;

    const float*          wrow = W + (size_t)ncol * H_SIZE + k0 + klane;
    const unsigned short* arow = A + (size_t)(lane & 15) * H_SIZE + k0 + klane;

    f32x4 acc[4] = {};
    for (int k = 0; k < KCHUNK; k += 32) {
        float4 wa = *(const float4*)(wrow + k);
        float4 wb = *(const float4*)(wrow + k + 4);
        bf16x8 bf = cvt8(wa, wb);
        #pragma unroll
        for (int m = 0; m < 4; ++m) {
            bf16x8 af = *(const bf16x8*)(const void*)(arow + (size_t)m * 16 * H_SIZE + k);
            acc[m] = __builtin_amdgcn_mfma_f32_16x16x32_bf16(af, bf, acc[m], 0, 0, 0);
        }
    }
    float* yp = Yp + (size_t)blockIdx.y * 64 * N;
    #pragma unroll
    for (int m = 0; m < 4; ++m)
        #pragma unroll
        for (int j = 0; j < 4; ++j)
            yp[(size_t)(m * 16 + (lane >> 4) * 4 + j) * N + ncol] = acc[m][j];
}

// ---------------- fused K-split reduce + RoPE for QKV ----------------
__global__ __launch_bounds__(256)
void qkv_reduce_rope(const float* __restrict__ Yp, float* __restrict__ qkv,
                     const int* __restrict__ positions) {
    const int s   = blockIdx.x;
    const int idx = blockIdx.y * 256 + threadIdx.x;
    const float pos = (float)positions[s];
    if (idx < 2560) {
        const int head = idx >> 6, d = idx & 63;
        const int j1 = (head < N_HEADS ? head * HEAD_DIM
                                       : Q_SIZE + (head - N_HEADS) * HEAD_DIM) + d;
        const int j2 = j1 + 64;
        float x1 = 0.f, x2 = 0.f;
        #pragma unroll
        for (int c = 0; c < KSPLIT; ++c) {
            x1 += Yp[((size_t)c * 64 + s) * QKV_OUT + j1];
            x2 += Yp[((size_t)c * 64 + s) * QKV_OUT + j2];
        }
        const float inv_freq = powf(10000.0f, -(float)d / 64.0f);
        const float ang = pos * inv_freq;
        const float cs = cosf(ang), sn = sinf(ang);
        qkv[(size_t)s * QKV_OUT + j1] = x1 * cs - x2 * sn;
        qkv[(size_t)s * QKV_OUT + j2] = x2 * cs + x1 * sn;
    } else if (idx < 3584) {
        const int j = Q_SIZE + KV_SIZE + (idx - 2560);
        float v = 0.f;
        #pragma unroll
        for (int c = 0; c < KSPLIT; ++c)
            v += Yp[((size_t)c * 64 + s) * QKV_OUT + j];
        qkv[(size_t)s * QKV_OUT + j] = v;
    }
}

__global__ __launch_bounds__(256)
void reduce_ksplit(const float* __restrict__ Yp, float* __restrict__ Y, int total) {
    int i = blockIdx.x * 256 + threadIdx.x;
    if (i >= total) return;
    float s = 0.f;
    #pragma unroll
    for (int c = 0; c < KSPLIT; ++c) s += Yp[(size_t)c * total + i];
    Y[i] = s;
}

// ---------------- Flash-decode attention, whole-cache-block decomposition ----------------
// grid (NUM_SEQS, NCHUNK); block 256 = 4 waves. Chunk = 64 tokens = 4 cache blocks.
// Wave w reads cache block c*4+w (64 KB contiguous): lane l owns rows (tok,h) = l and l+64.
__global__ __launch_bounds__(256)
void attn_chunk(const float* __restrict__ qkv,
                const float* __restrict__ k_cache,
                const float* __restrict__ v_cache,
                const int*   __restrict__ block_tables,
                const int*   __restrict__ context_lens,
                float* __restrict__ pacc,   // [s][c][32 hg][128]
                float* __restrict__ pml) {  // [s][c][32 hg][2]
    const int s = blockIdx.x;
    const int c = blockIdx.y;
    const int ctx = context_lens[s];
    if (c * CHUNK >= ctx) return;
    const int pos = ctx - 1;
    const int nvalid = min(CHUNK, ctx - c * CHUNK);

    __shared__ float qs[32][132];   // 32 q-heads x 128 dims, pad 132 (16B-aligned rows)
    __shared__ float sc[32][65];    // scores [q-head][token]

    const int tid  = threadIdx.x;
    const int w    = tid >> 6;
    const int lane = tid & 63;

    // load roped q into LDS (contiguous first 4096 floats of qkv row)
    {
        const float* qsrc = qkv + (size_t)s * QKV_OUT;
        #pragma unroll
        for (int r = 0; r < 4; ++r) {
            int i = (tid + r * 256) * 4;         // float index 0..4095
            float4 v = *(const float4*)(qsrc + i);
            *(float4*)(&qs[i >> 7][i & 127]) = v;
        }
    }
    __syncthreads();

    const int*   bt   = block_tables + s * BLOCKS_PER_SEQ;
    const float* ksec = qkv + (size_t)s * QKV_OUT + Q_SIZE;   // new k [8][128]
    const float* vsec = ksec + KV_SIZE;                        // new v [8][128]

    // ---- phase 1: scores. wave w = cache block c*4+w, tokens w*16..w*16+15 ----
    {
        const int blk = bt[c * 4 + w];
        const float* kbase = k_cache + (size_t)blk * (BLK_SZ * N_KV * HEAD_DIM);
        const int h  = lane & 7;
        const int t0 = w * 16 + (lane >> 3);   // token-in-chunk for row0
        const int t1 = t0 + 8;
        const int T0 = c * CHUNK + t0;
        const int T1 = c * CHUNK + t1;
        const float* kp0 = (T0 == pos) ? (ksec + h * HEAD_DIM)
                         : (kbase + (size_t)((t0 & 15) * N_KV + h) * HEAD_DIM);
        const float* kp1 = (T1 == pos) ? (ksec + h * HEAD_DIM)
                         : (kbase + (size_t)((t1 & 15) * N_KV + h) * HEAD_DIM);
        float d0[4] = {}, d1[4] = {};
        #pragma unroll 4
        for (int j = 0; j < 32; ++j) {
            float4 k0 = *(const float4*)(kp0 + j * 4);
            float4 k1 = *(const float4*)(kp1 + j * 4);
            #pragma unroll
            for (int g = 0; g < 4; ++g) {
                float4 q4 = *(const float4*)(&qs[h * 4 + g][j * 4]);
                d0[g] = fmaf(k0.x,q4.x, fmaf(k0.y,q4.y, fmaf(k0.z,q4.z, fmaf(k0.w,q4.w, d0[g]))));
                d1[g] = fmaf(k1.x,q4.x, fmaf(k1.y,q4.y, fmaf(k1.z,q4.z, fmaf(k1.w,q4.w, d1[g]))));
            }
        }
        #pragma unroll
        for (int g = 0; g < 4; ++g) {
            sc[h * 4 + g][t0] = (t0 < nvalid) ? d0[g] * ATT_SCALE : -1e30f;
            sc[h * 4 + g][t1] = (t1 < nvalid) ? d1[g] * ATT_SCALE : -1e30f;
        }
    }
    __syncthreads();

    // ---- chunk softmax: wave w owns 8 q-heads; 8 lanes per head ----
    {
        const int hg = w * 8 + (lane >> 3);
        const int tk = lane & 7;
        float m = -1e30f;
        #pragma unroll
        for (int k = 0; k < 8; ++k) m = fmaxf(m, sc[hg][tk + k * 8]);
        m = fmaxf(m, __shfl_xor(m, 1));
        m = fmaxf(m, __shfl_xor(m, 2));
        m = fmaxf(m, __shfl_xor(m, 4));
        float l = 0.f;
        #pragma unroll
        for (int k = 0; k < 8; ++k) {
            float e = __expf(sc[hg][tk + k * 8] - m);
            sc[hg][tk + k * 8] = e;
            l += e;
        }
        l += __shfl_xor(l, 1);
        l += __shfl_xor(l, 2);
        l += __shfl_xor(l, 4);
        if (tk == 0) {
            size_t ib = (((size_t)s * NCHUNK + c) * 32 + hg) * 2;
            pml[ib] = m; pml[ib + 1] = l;
        }
    }
    __syncthreads();

    // ---- phase 2: PV. wave w accumulates kv-heads w*2, w*2+1; lane = (kvh, dim quad) ----
    {
        const int kvh = w * 2 + (lane >> 5);
        const int dq  = (lane & 31) * 4;
        const float* vnewp = vsec + (size_t)kvh * HEAD_DIM + dq;
        float4 a0 = {0,0,0,0}, a1 = {0,0,0,0}, a2 = {0,0,0,0}, a3 = {0,0,0,0};
        for (int cb = 0; cb < 4; ++cb) {
            const int tbase = cb * 16;
            if (tbase >= nvalid) break;
            const int blk = bt[c * 4 + cb];
            const float* vbase = v_cache + (size_t)blk * (BLK_SZ * N_KV * HEAD_DIM)
                               + (size_t)kvh * HEAD_DIM + dq;
            const int tmax = min(16, nvalid - tbase);
            for (int tt = 0; tt < tmax; ++tt) {
                const int t = tbase + tt;
                const float* vp = (c * CHUNK + t == pos) ? vnewp
                                : vbase + (size_t)tt * (N_KV * HEAD_DIM);
                float4 vv = *(const float4*)vp;
                float p0 = sc[kvh * 4 + 0][t];
                float p1 = sc[kvh * 4 + 1][t];
                float p2 = sc[kvh * 4 + 2][t];
                float p3 = sc[kvh * 4 + 3][t];
                a0.x = fmaf(p0, vv.x, a0.x); a0.y = fmaf(p0, vv.y, a0.y);
                a0.z = fmaf(p0, vv.z, a0.z); a0.w = fmaf(p0, vv.w, a0.w);
                a1.x = fmaf(p1, vv.x, a1.x); a1.y = fmaf(p1, vv.y, a1.y);
                a1.z = fmaf(p1, vv.z, a1.z); a1.w = fmaf(p1, vv.w, a1.w);
                a2.x = fmaf(p2, vv.x, a2.x); a2.y = fmaf(p2, vv.y, a2.y);
                a2.z = fmaf(p2, vv.z, a2.z); a2.w = fmaf(p2, vv.w, a2.w);
                a3.x = fmaf(p3, vv.x, a3.x); a3.y = fmaf(p3, vv.y, a3.y);
                a3.z = fmaf(p3, vv.z, a3.z); a3.w = fmaf(p3, vv.w, a3.w);
            }
        }
        size_t ob = ((((size_t)s * NCHUNK + c) * 32) + kvh * 4) * HEAD_DIM + dq;
        *(float4*)(pacc + ob)                 = a0;
        *(float4*)(pacc + ob + HEAD_DIM)      = a1;
        *(float4*)(pacc + ob + 2 * HEAD_DIM)  = a2;
        *(float4*)(pacc + ob + 3 * HEAD_DIM)  = a3;
    }
}

// ---------------- combine chunk partials; emit bf16 for the O-GEMM ----------------
// grid (NUM_SEQS, 32 q-heads); block 64 (lane = dim pair)
__global__ __launch_bounds__(64)
void attn_reduce(const float* __restrict__ pacc, const float* __restrict__ pml,
                 const int* __restrict__ context_lens, unsigned short* __restrict__ outbf) {
    const int s    = blockIdx.x;
    const int hg   = blockIdx.y;
    const int lane = threadIdx.x;
    const int ctx  = context_lens[s];
    const int nc   = (ctx + CHUNK - 1) / CHUNK;

    float M = -1e30f;
    for (int cc = 0; cc < nc; ++cc)
        M = fmaxf(M, pml[(((size_t)s * NCHUNK + cc) * 32 + hg) * 2]);
    float ox = 0.f, oy = 0.f, L = 0.f;
    for (int cc = 0; cc < nc; ++cc) {
        size_t idx = ((size_t)s * NCHUNK + cc) * 32 + hg;
        float wgt = __expf(pml[idx * 2] - M);
        L = fmaf(wgt, pml[idx * 2 + 1], L);
        float2 pa = *(const float2*)(pacc + idx * HEAD_DIM + lane * 2);
        ox = fmaf(wgt, pa.x, ox);
        oy = fmaf(wgt, pa.y, oy);
    }
    float inv = 1.0f / L;
    unsigned short* op = outbf + (size_t)s * Q_SIZE + hg * HEAD_DIM;
    ushort2 o2 = { (unsigned short)f2bf(ox * inv), (unsigned short)f2bf(oy * inv) };
    *(ushort2*)(op + lane * 2) = o2;
}

extern "C" void kernel_launch(void* const* d_in, const int* in_sizes, int n_in,
                              void* d_out, int out_size, void* d_ws, size_t ws_size,
                              hipStream_t stream) {
    const int*   positions    = (const int*)  d_in[0];
    const float* hidden       = (const float*)d_in[1];
    const float* k_cache      = (const float*)d_in[2];
    const float* v_cache      = (const float*)d_in[3];
    const int*   block_tables = (const int*)  d_in[4];
    const int*   context_lens = (const int*)  d_in[5];
    const float* W_qkv        = (const float*)d_in[6];
    const float* W_o          = (const float*)d_in[7];
    float* out = (float*)d_out;

    float* qkv_ws = (float*)d_ws;                                     // 393216 f
    unsigned short* hidden_bf = (unsigned short*)(qkv_ws + (size_t)NUM_SEQS * QKV_OUT);
    unsigned short* attn_bf   = hidden_bf + (size_t)NUM_SEQS * H_SIZE;
    float* scratch = (float*)(attn_bf + (size_t)NUM_SEQS * H_SIZE);
    // scratch reused: QKV partials (8*393216 f) -> attn pacc/pml -> O partials
    float* pacc = scratch;                                             // 64*32*32*128 f
    float* pml  = scratch + (size_t)NUM_SEQS * NCHUNK * 32 * HEAD_DIM; // 64*32*32*2 f

    // 0) X -> bf16 (once)
    cvt_bf16<<<(NUM_SEQS * H_SIZE / 4 + 255) / 256, 256, 0, stream>>>(
        hidden, hidden_bf, NUM_SEQS * H_SIZE / 4);
    // 1) QKV projection + fused reduce+RoPE
    gemm_mfma<<<dim3(QKV_OUT / 64, KSPLIT), 256, 0, stream>>>(hidden_bf, W_qkv, scratch, QKV_OUT);
    qkv_reduce_rope<<<dim3(NUM_SEQS, 14), 256, 0, stream>>>(scratch, qkv_ws, positions);
    // 2) flash-decode attention (whole-cache-block reads)
    attn_chunk<<<dim3(NUM_SEQS, NCHUNK), 256, 0, stream>>>(
        qkv_ws, k_cache, v_cache, block_tables, context_lens, pacc, pml);
    attn_reduce<<<dim3(NUM_SEQS, 32), 64, 0, stream>>>(pacc, pml, context_lens, attn_bf);
    // 3) output projection + reduce
    gemm_mfma<<<dim3(Q_SIZE / 64, KSPLIT), 256, 0, stream>>>(attn_bf, W_o, scratch, Q_SIZE);
    reduce_ksplit<<<(NUM_SEQS * Q_SIZE + 255) / 256, 256, 0, stream>>>(scratch, out, NUM_SEQS * Q_SIZE);
}

// Round 7
// 251.245 us; speedup vs baseline: 1.3772x; 1.0355x over previous
//
#include <hip/hip_runtime.h>
#include <math.h>

#define H_SIZE   4096
#define N_HEADS  32
#define N_KV     8
#define HEAD_DIM 128
#define GROUP    4
#define Q_SIZE   4096
#define KV_SIZE  1024
#define QKV_OUT  6144          // Q_SIZE + 2*KV_SIZE
#define NUM_SEQS 64
#define MAX_CTX  2048
#define BLK_SZ   16
#define BLOCKS_PER_SEQ 128
#define ATT_SCALE 0.08838834764831845f   // 128^-0.5

#define CHUNK    64            // tokens per attn workgroup
#define NCHUNK   32            // MAX_CTX / CHUNK
#define KSPLIT   8
#define KCHUNK   512           // H_SIZE / KSPLIT

typedef __attribute__((ext_vector_type(8))) short bf16x8;
typedef __attribute__((ext_vector_type(4))) float f32x4;

__device__ __forceinline__ short f2bf(float f) {
    return __builtin_bit_cast(short, (__bf16)f);   // lowers to v_cvt_pk_bf16_f32
}

__device__ __forceinline__ bf16x8 cvt8(float4 a, float4 b) {
    bf16x8 r;
    r[0]=f2bf(a.x); r[1]=f2bf(a.y); r[2]=f2bf(a.z); r[3]=f2bf(a.w);
    r[4]=f2bf(b.x); r[5]=f2bf(b.y); r[6]=f2bf(b.z); r[7]=f2bf(b.w);
    return r;
}

// ---------------- fp32 -> bf16 bulk convert (X operand, done once) ----------------
__global__ __launch_bounds__(256)
void cvt_bf16(const float* __restrict__ in, unsigned short* __restrict__ out, int n4) {
    int i = blockIdx.x * 256 + threadIdx.x;
    if (i >= n4) return;
    float4 v = *(const float4*)(in + (size_t)i * 4);
    ushort2 lo = { (unsigned short)f2bf(v.x), (unsigned short)f2bf(v.y) };
    ushort2 hi = { (unsigned short)f2bf(v.z), (unsigned short)f2bf(v.w) };
    *(ushort2*)(out + (size_t)i * 4)     = lo;
    *(ushort2*)(out + (size_t)i * 4 + 2) = hi;
}

// ---------------- MFMA GEMM: Yp[c][64][N] = A[64][4096] @ W[N][4096]^T ----------
__global__ __launch_bounds__(256)
void gemm_mfma(const unsigned short* __restrict__ A, const float* __restrict__ W,
               float* __restrict__ Yp, int N) {
    const int n0   = blockIdx.x * 64;
    const int k0   = blockIdx.y * KCHUNK;
    const int wave = threadIdx.x >> 6;
    const int lane = threadIdx.x & 63;
    const int ncol = n0 + wave * 16 + (lane & 15);
    const int klane = (lane >> 4) * 8;

    const float*          wrow = W + (size_t)ncol * H_SIZE + k0 + klane;
    const unsigned short* arow = A + (size_t)(lane & 15) * H_SIZE + k0 + klane;

    f32x4 acc[4] = {};
    for (int k = 0; k < KCHUNK; k += 32) {
        float4 wa = *(const float4*)(wrow + k);
        float4 wb = *(const float4*)(wrow + k + 4);
        bf16x8 bf = cvt8(wa, wb);
        #pragma unroll
        for (int m = 0; m < 4; ++m) {
            bf16x8 af = *(const bf16x8*)(const void*)(arow + (size_t)m * 16 * H_SIZE + k);
            acc[m] = __builtin_amdgcn_mfma_f32_16x16x32_bf16(af, bf, acc[m], 0, 0, 0);
        }
    }
    float* yp = Yp + (size_t)blockIdx.y * 64 * N;
    #pragma unroll
    for (int m = 0; m < 4; ++m)
        #pragma unroll
        for (int j = 0; j < 4; ++j)
            yp[(size_t)(m * 16 + (lane >> 4) * 4 + j) * N + ncol] = acc[m][j];
}

// ---------------- fused K-split reduce + RoPE for QKV ----------------
__global__ __launch_bounds__(256)
void qkv_reduce_rope(const float* __restrict__ Yp, float* __restrict__ qkv,
                     const int* __restrict__ positions) {
    const int s   = blockIdx.x;
    const int idx = blockIdx.y * 256 + threadIdx.x;
    const float pos = (float)positions[s];
    if (idx < 2560) {
        const int head = idx >> 6, d = idx & 63;
        const int j1 = (head < N_HEADS ? head * HEAD_DIM
                                       : Q_SIZE + (head - N_HEADS) * HEAD_DIM) + d;
        const int j2 = j1 + 64;
        float x1 = 0.f, x2 = 0.f;
        #pragma unroll
        for (int c = 0; c < KSPLIT; ++c) {
            x1 += Yp[((size_t)c * 64 + s) * QKV_OUT + j1];
            x2 += Yp[((size_t)c * 64 + s) * QKV_OUT + j2];
        }
        const float inv_freq = powf(10000.0f, -(float)d / 64.0f);
        const float ang = pos * inv_freq;
        const float cs = cosf(ang), sn = sinf(ang);
        qkv[(size_t)s * QKV_OUT + j1] = x1 * cs - x2 * sn;
        qkv[(size_t)s * QKV_OUT + j2] = x2 * cs + x1 * sn;
    } else if (idx < 3584) {
        const int j = Q_SIZE + KV_SIZE + (idx - 2560);
        float v = 0.f;
        #pragma unroll
        for (int c = 0; c < KSPLIT; ++c)
            v += Yp[((size_t)c * 64 + s) * QKV_OUT + j];
        qkv[(size_t)s * QKV_OUT + j] = v;
    }
}

__global__ __launch_bounds__(256)
void reduce_ksplit(const float* __restrict__ Yp, float* __restrict__ Y, int total) {
    int i = blockIdx.x * 256 + threadIdx.x;
    if (i >= total) return;
    float s = 0.f;
    #pragma unroll
    for (int c = 0; c < KSPLIT; ++c) s += Yp[(size_t)c * total + i];
    Y[i] = s;
}

// ---------------- Flash-decode attention, fine-grained for occupancy ----------------
// grid (NUM_SEQS*N_KV, NCHUNK); block 128 = 2 waves. Chunk = 64 tokens, one kv-head.
// K phase: 2 lanes/token, each lane streams a contiguous 256B half-row (line-merged).
// PV phase: lane = dim-pair, one contiguous 512B V row per wave-instruction.
__global__ __launch_bounds__(128)
void attn_chunk(const float* __restrict__ qkv,
                const float* __restrict__ k_cache,
                const float* __restrict__ v_cache,
                const int*   __restrict__ block_tables,
                const int*   __restrict__ context_lens,
                float* __restrict__ pacc,   // [sh][c][g][128]
                float* __restrict__ pml) {  // [sh][c][g][2]
    const int sh = blockIdx.x;
    const int s  = sh >> 3;
    const int h  = sh & 7;
    const int c  = blockIdx.y;
    const int ctx = context_lens[s];
    if (c * CHUNK >= ctx) return;
    const int pos = ctx - 1;
    const int nv = min(CHUNK, ctx - c * CHUNK);

    __shared__ float qs[GROUP][HEAD_DIM];     // 2 KB
    __shared__ float sc[GROUP][CHUNK];        // 1 KB
    __shared__ float red[2][GROUP][HEAD_DIM]; // 4 KB

    const int tid  = threadIdx.x;
    const int w    = tid >> 6;
    const int lane = tid & 63;

    {   // q for this group's 4 heads: 512 contiguous floats
        int i = tid * 4;
        const float* qsrc = qkv + (size_t)s * QKV_OUT + h * (GROUP * HEAD_DIM);
        *(float4*)(&qs[i >> 7][i & 127]) = *(const float4*)(qsrc + i);
    }
    __syncthreads();

    const int*   bt   = block_tables + s * BLOCKS_PER_SEQ;
    const float* ksec = qkv + (size_t)s * QKV_OUT + Q_SIZE + h * HEAD_DIM;
    const float* vsec = qkv + (size_t)s * QKV_OUT + Q_SIZE + KV_SIZE + h * HEAD_DIM;

    // ---- K phase: token tk = w*32 + lane/2; lane&1 picks half-row (64 dims) ----
    {
        const int tk   = w * 32 + (lane >> 1);
        const int half = lane & 1;
        const int T    = c * CHUNK + tk;
        float d0 = 0.f, d1 = 0.f, d2 = 0.f, d3 = 0.f;
        if (tk < nv) {
            const int blk = bt[c * 4 + (tk >> 4)];
            const float* kp = (T == pos) ? ksec
                : k_cache + ((size_t)(blk * BLK_SZ + (tk & 15)) * N_KV + h) * HEAD_DIM;
            kp += half * 64;
            const float* q0 = &qs[0][half * 64];
            const float* q1 = &qs[1][half * 64];
            const float* q2 = &qs[2][half * 64];
            const float* q3 = &qs[3][half * 64];
            #pragma unroll
            for (int b = 0; b < 2; ++b) {
                float4 kv[8];
                #pragma unroll
                for (int j = 0; j < 8; ++j) kv[j] = *(const float4*)(kp + b * 32 + j * 4);
                #pragma unroll
                for (int j = 0; j < 8; ++j) {
                    const float4 A = kv[j];
                    const float4 x0 = *(const float4*)(q0 + b * 32 + j * 4);
                    const float4 x1 = *(const float4*)(q1 + b * 32 + j * 4);
                    const float4 x2 = *(const float4*)(q2 + b * 32 + j * 4);
                    const float4 x3 = *(const float4*)(q3 + b * 32 + j * 4);
                    d0 = fmaf(A.x,x0.x, fmaf(A.y,x0.y, fmaf(A.z,x0.z, fmaf(A.w,x0.w, d0))));
                    d1 = fmaf(A.x,x1.x, fmaf(A.y,x1.y, fmaf(A.z,x1.z, fmaf(A.w,x1.w, d1))));
                    d2 = fmaf(A.x,x2.x, fmaf(A.y,x2.y, fmaf(A.z,x2.z, fmaf(A.w,x2.w, d2))));
                    d3 = fmaf(A.x,x3.x, fmaf(A.y,x3.y, fmaf(A.z,x3.z, fmaf(A.w,x3.w, d3))));
                }
            }
        }
        d0 += __shfl_xor(d0, 1);
        d1 += __shfl_xor(d1, 1);
        d2 += __shfl_xor(d2, 1);
        d3 += __shfl_xor(d3, 1);
        if (half == 0) {
            const bool v = (tk < nv);
            sc[0][tk] = v ? d0 * ATT_SCALE : -1e30f;
            sc[1][tk] = v ? d1 * ATT_SCALE : -1e30f;
            sc[2][tk] = v ? d2 * ATT_SCALE : -1e30f;
            sc[3][tk] = v ? d3 * ATT_SCALE : -1e30f;
        }
    }
    __syncthreads();

    // ---- softmax: wave w handles heads 2w, 2w+1 (lane = token) ----
    #pragma unroll
    for (int gg = 0; gg < 2; ++gg) {
        const int g = w * 2 + gg;
        const float v = sc[g][lane];
        float m = v;
        #pragma unroll
        for (int off = 32; off; off >>= 1) m = fmaxf(m, __shfl_xor(m, off));
        const float e = __expf(v - m);
        float l = e;
        #pragma unroll
        for (int off = 32; off; off >>= 1) l += __shfl_xor(l, off);
        sc[g][lane] = e;
        if (lane == 0) {
            size_t ib = (((size_t)sh * NCHUNK + c) * GROUP + g) * 2;
            pml[ib] = m; pml[ib + 1] = l;
        }
    }
    __syncthreads();

    // ---- PV: wave w owns tokens w*32..+31; lane = dim pair ----
    {
        float2 a0 = {0,0}, a1 = {0,0}, a2 = {0,0}, a3 = {0,0};
        const int t0 = w * 32;
        const int tmax = min(32, nv - t0);
        #pragma unroll 4
        for (int tt = 0; tt < tmax; ++tt) {
            const int tk = t0 + tt;
            const int T  = c * CHUNK + tk;
            const int blk = bt[c * 4 + (tk >> 4)];
            const float* vp = (T == pos) ? vsec
                : v_cache + ((size_t)(blk * BLK_SZ + (tk & 15)) * N_KV + h) * HEAD_DIM;
            const float2 vv = *(const float2*)(vp + lane * 2);
            const float p0 = sc[0][tk], p1 = sc[1][tk], p2 = sc[2][tk], p3 = sc[3][tk];
            a0.x = fmaf(p0, vv.x, a0.x); a0.y = fmaf(p0, vv.y, a0.y);
            a1.x = fmaf(p1, vv.x, a1.x); a1.y = fmaf(p1, vv.y, a1.y);
            a2.x = fmaf(p2, vv.x, a2.x); a2.y = fmaf(p2, vv.y, a2.y);
            a3.x = fmaf(p3, vv.x, a3.x); a3.y = fmaf(p3, vv.y, a3.y);
        }
        *(float2*)(&red[w][0][lane * 2]) = a0;
        *(float2*)(&red[w][1][lane * 2]) = a1;
        *(float2*)(&red[w][2][lane * 2]) = a2;
        *(float2*)(&red[w][3][lane * 2]) = a3;
    }
    __syncthreads();

    {   // combine the 2 waves' partials; 128 threads x float4 = 4 heads x 128 dims
        const int g = tid >> 5, d = (tid & 31) * 4;
        float4 r0 = *(const float4*)(&red[0][g][d]);
        float4 r1 = *(const float4*)(&red[1][g][d]);
        float4 o  = { r0.x + r1.x, r0.y + r1.y, r0.z + r1.z, r0.w + r1.w };
        size_t ob = (((size_t)sh * NCHUNK + c) * GROUP + g) * HEAD_DIM + d;
        *(float4*)(pacc + ob) = o;
    }
}

// ---------------- combine chunk partials; emit bf16 for the O-GEMM ----------------
__global__ __launch_bounds__(256)
void attn_reduce(const float* __restrict__ pacc, const float* __restrict__ pml,
                 const int* __restrict__ context_lens, unsigned short* __restrict__ outbf) {
    const int sh = blockIdx.x;
    const int s  = sh >> 3;
    const int h  = sh & 7;
    const int g    = threadIdx.x >> 6;
    const int lane = threadIdx.x & 63;
    const int ctx = context_lens[s];
    const int nc  = (ctx + CHUNK - 1) / CHUNK;

    float M = -1e30f;
    for (int cc = 0; cc < nc; ++cc)
        M = fmaxf(M, pml[(((size_t)sh * NCHUNK + cc) * GROUP + g) * 2]);
    float ox = 0.f, oy = 0.f, L = 0.f;
    for (int cc = 0; cc < nc; ++cc) {
        size_t idx = ((size_t)sh * NCHUNK + cc) * GROUP + g;
        float w = __expf(pml[idx*2] - M);
        L = fmaf(w, pml[idx*2+1], L);
        float2 pa = *(const float2*)(pacc + idx * HEAD_DIM + lane*2);
        ox = fmaf(w, pa.x, ox);
        oy = fmaf(w, pa.y, oy);
    }
    float inv = 1.0f / L;
    unsigned short* op = outbf + (size_t)s * Q_SIZE + (h * GROUP + g) * HEAD_DIM;
    ushort2 o2 = { (unsigned short)f2bf(ox * inv), (unsigned short)f2bf(oy * inv) };
    *(ushort2*)(op + lane * 2) = o2;
}

extern "C" void kernel_launch(void* const* d_in, const int* in_sizes, int n_in,
                              void* d_out, int out_size, void* d_ws, size_t ws_size,
                              hipStream_t stream) {
    const int*   positions    = (const int*)  d_in[0];
    const float* hidden       = (const float*)d_in[1];
    const float* k_cache      = (const float*)d_in[2];
    const float* v_cache      = (const float*)d_in[3];
    const int*   block_tables = (const int*)  d_in[4];
    const int*   context_lens = (const int*)  d_in[5];
    const float* W_qkv        = (const float*)d_in[6];
    const float* W_o          = (const float*)d_in[7];
    float* out = (float*)d_out;

    float* qkv_ws = (float*)d_ws;                                     // 393216 f
    unsigned short* hidden_bf = (unsigned short*)(qkv_ws + (size_t)NUM_SEQS * QKV_OUT);
    unsigned short* attn_bf   = hidden_bf + (size_t)NUM_SEQS * H_SIZE;
    float* scratch = (float*)(attn_bf + (size_t)NUM_SEQS * H_SIZE);
    // scratch reused: QKV partials (8*393216 f) -> attn pacc/pml -> O partials
    float* pacc = scratch;                                             // 64*8*32*4*128 f
    float* pml  = scratch + (size_t)NUM_SEQS * N_KV * NCHUNK * GROUP * HEAD_DIM;

    // 0) X -> bf16 (once)
    cvt_bf16<<<(NUM_SEQS * H_SIZE / 4 + 255) / 256, 256, 0, stream>>>(
        hidden, hidden_bf, NUM_SEQS * H_SIZE / 4);
    // 1) QKV projection + fused reduce+RoPE
    gemm_mfma<<<dim3(QKV_OUT / 64, KSPLIT), 256, 0, stream>>>(hidden_bf, W_qkv, scratch, QKV_OUT);
    qkv_reduce_rope<<<dim3(NUM_SEQS, 14), 256, 0, stream>>>(scratch, qkv_ws, positions);
    // 2) flash-decode attention (fine-grained: 16384 wg, 2 waves each)
    attn_chunk<<<dim3(NUM_SEQS * N_KV, NCHUNK), 128, 0, stream>>>(
        qkv_ws, k_cache, v_cache, block_tables, context_lens, pacc, pml);
    attn_reduce<<<NUM_SEQS * N_KV, 256, 0, stream>>>(pacc, pml, context_lens, attn_bf);
    // 3) output projection + reduce
    gemm_mfma<<<dim3(Q_SIZE / 64, KSPLIT), 256, 0, stream>>>(attn_bf, W_o, scratch, Q_SIZE);
    reduce_ksplit<<<(NUM_SEQS * Q_SIZE + 255) / 256, 256, 0, stream>>>(scratch, out, NUM_SEQS * Q_SIZE);
}